// Round 1
// baseline (710.267 us; speedup 1.0000x reference)
//
#include <hip/hip_runtime.h>
#include <stdint.h>

#define MTOT  16384   // B*S
#define KDIM  4096    // INTER
#define NDIM  1024    // HID
#define CLIPV 2.5f

typedef __attribute__((ext_vector_type(4)))  int i32x4;
typedef __attribute__((ext_vector_type(16))) int i32x16;
typedef __attribute__((address_space(3))) void lvoid;
typedef __attribute__((address_space(1))) void gvoid;

#define G2L16(g, l) __builtin_amdgcn_global_load_lds((gvoid*)(g), (lvoid*)(l), 16, 0, 0)

// ---------------- max|x| reduction (uint-bit atomicMax works for non-neg floats) ----
__global__ void maxabs_kernel(const float4* __restrict__ x, int n4,
                              unsigned* __restrict__ slot) {
  float m = 0.f;
  for (int i = blockIdx.x * blockDim.x + threadIdx.x; i < n4;
       i += gridDim.x * blockDim.x) {
    float4 v = x[i];
    m = fmaxf(m, fmaxf(fmaxf(fabsf(v.x), fabsf(v.y)),
                       fmaxf(fabsf(v.z), fabsf(v.w))));
  }
#pragma unroll
  for (int off = 32; off > 0; off >>= 1) m = fmaxf(m, __shfl_xor(m, off));
  if ((threadIdx.x & 63) == 0) atomicMax(slot, __float_as_uint(m));
}

// ---------------- symmetric int8 quantization: q = rint(clip(x)*127/m) ------------
__global__ void quant_kernel(const float4* __restrict__ x,
                             unsigned* __restrict__ q, int n4,
                             const unsigned* __restrict__ slot) {
  const float m = fminf(__uint_as_float(*slot), CLIPV);  // m = min(maxabs, clip)
  const float s = 127.0f / m;
  for (int i = blockIdx.x * blockDim.x + threadIdx.x; i < n4;
       i += gridDim.x * blockDim.x) {
    float4 v = x[i];
    int a = (int)rintf(fminf(fmaxf(v.x, -CLIPV), CLIPV) * s);
    int b = (int)rintf(fminf(fmaxf(v.y, -CLIPV), CLIPV) * s);
    int c = (int)rintf(fminf(fmaxf(v.z, -CLIPV), CLIPV) * s);
    int d = (int)rintf(fminf(fmaxf(v.w, -CLIPV), CLIPV) * s);
    q[i] = (unsigned)(a & 255) | ((unsigned)(b & 255) << 8) |
           ((unsigned)(c & 255) << 16) | ((unsigned)(d & 255) << 24);
  }
}

// ---------------- int8 GEMM: C[m][n] = S * sum_k qA[m][k]*qB[n][k] -----------------
// 128x128 block tile, BK=64, 4 waves (2x2), wave tile 64x64 via 2x2 mfma_i32_32x32x32_i8.
// LDS slots (16B) XOR-swizzled: data(row,c) at slot row*4 + (c ^ ((row>>1)&3)).
__global__ __launch_bounds__(256) void gemm_i8(
    const int8_t* __restrict__ qA, const int8_t* __restrict__ qB,
    float* __restrict__ out, const unsigned* __restrict__ slot_x,
    const unsigned* __restrict__ slot_w) {
  __shared__ __align__(16) int8_t As[128 * 64];
  __shared__ __align__(16) int8_t Bs[128 * 64];

  const int t  = threadIdx.x;
  const int l  = t & 63;
  const int w  = t >> 6;
  const int wm = (w & 1) * 64;
  const int wn = (w >> 1) * 64;
  const int lr = l & 31;   // m/n index within 32-tile
  const int lh = l >> 5;   // k-chunk half

  const long m0 = (long)blockIdx.y * 128;
  const long n0 = (long)blockIdx.x * 128;

  i32x16 acc[2][2] = {};

  // staging: thread t covers 16B-slots s0=t and s1=t+256 of each 512-slot tile
  const int s0 = t, s1 = t + 256;
  const int8_t* gA0 = qA + (m0 + (s0 >> 2)) * KDIM + (((s0 & 3) ^ ((s0 >> 3) & 3)) * 16);
  const int8_t* gA1 = qA + (m0 + (s1 >> 2)) * KDIM + (((s1 & 3) ^ ((s1 >> 3) & 3)) * 16);
  const int8_t* gB0 = qB + (n0 + (s0 >> 2)) * KDIM + (((s0 & 3) ^ ((s0 >> 3) & 3)) * 16);
  const int8_t* gB1 = qB + (n0 + (s1 >> 2)) * KDIM + (((s1 & 3) ^ ((s1 >> 3) & 3)) * 16);
  int8_t* lA0 = As + (t & 192) * 16;           // wave-uniform LDS bases
  int8_t* lA1 = As + ((t & 192) + 256) * 16;
  int8_t* lB0 = Bs + (t & 192) * 16;
  int8_t* lB1 = Bs + ((t & 192) + 256) * 16;

  // fragment LDS byte offsets (swizzled), [kk][tile]
  int aoff[2][2], boff[2][2];
#pragma unroll
  for (int kk = 0; kk < 2; ++kk)
#pragma unroll
    for (int mt = 0; mt < 2; ++mt) {
      const int c  = kk * 2 + lh;
      const int ra = wm + mt * 32 + lr;
      const int rb = wn + mt * 32 + lr;
      aoff[kk][mt] = ra * 64 + ((c ^ ((ra >> 1) & 3)) * 16);
      boff[kk][mt] = rb * 64 + ((c ^ ((rb >> 1) & 3)) * 16);
    }

  for (int k0 = 0; k0 < KDIM; k0 += 64) {
    G2L16(gA0 + k0, lA0);
    G2L16(gA1 + k0, lA1);
    G2L16(gB0 + k0, lB0);
    G2L16(gB1 + k0, lB1);
    __syncthreads();   // compiler drains vmcnt(0) before s_barrier
#pragma unroll
    for (int kk = 0; kk < 2; ++kk) {
      i32x4 af0 = *(const i32x4*)(As + aoff[kk][0]);
      i32x4 af1 = *(const i32x4*)(As + aoff[kk][1]);
      i32x4 bf0 = *(const i32x4*)(Bs + boff[kk][0]);
      i32x4 bf1 = *(const i32x4*)(Bs + boff[kk][1]);
      acc[0][0] = __builtin_amdgcn_mfma_i32_32x32x32_i8(af0, bf0, acc[0][0], 0, 0, 0);
      acc[0][1] = __builtin_amdgcn_mfma_i32_32x32x32_i8(af0, bf1, acc[0][1], 0, 0, 0);
      acc[1][0] = __builtin_amdgcn_mfma_i32_32x32x32_i8(af1, bf0, acc[1][0], 0, 0, 0);
      acc[1][1] = __builtin_amdgcn_mfma_i32_32x32x32_i8(af1, bf1, acc[1][1], 0, 0, 0);
    }
    __syncthreads();
  }

  const float mx = fminf(__uint_as_float(*slot_x), CLIPV);
  const float mw = fminf(__uint_as_float(*slot_w), CLIPV);
  const float S  = mx * mw * (1.0f / (127.0f * 127.0f));

  // C/D layout (32x32, dtype-independent): col=lane&31, row=(r&3)+8*(r>>2)+4*(lane>>5)
#pragma unroll
  for (int mt = 0; mt < 2; ++mt)
#pragma unroll
    for (int nt = 0; nt < 2; ++nt)
#pragma unroll
      for (int r = 0; r < 16; ++r) {
        const long row = m0 + wm + mt * 32 + (r & 3) + 8 * (r >> 2) + 4 * lh;
        const long col = n0 + wn + nt * 32 + (l & 31);
        out[row * NDIM + col] = (float)acc[mt][nt][r] * S;
      }
}

// ---------------- fused bias + residual + LayerNorm (in-place on d_out) ------------
__global__ __launch_bounds__(256) void ln_kernel(
    float* __restrict__ h, const float* __restrict__ resid,
    const float* __restrict__ bias, const float* __restrict__ gamma,
    const float* __restrict__ beta) {
  __shared__ float red[8];
  const long row = blockIdx.x;
  const int t = threadIdx.x;
  float4* hp = (float4*)(h + row * NDIM);
  const float4* rp = (const float4*)(resid + row * NDIM);
  float4 y  = hp[t];
  float4 rv = rp[t];
  float4 bv = ((const float4*)bias)[t];
  y.x += rv.x + bv.x; y.y += rv.y + bv.y; y.z += rv.z + bv.z; y.w += rv.w + bv.w;
  float sum = y.x + y.y + y.z + y.w;
  float ss  = y.x * y.x + y.y * y.y + y.z * y.z + y.w * y.w;
#pragma unroll
  for (int off = 32; off > 0; off >>= 1) {
    sum += __shfl_xor(sum, off);
    ss  += __shfl_xor(ss, off);
  }
  if ((t & 63) == 0) { red[(t >> 6) * 2] = sum; red[(t >> 6) * 2 + 1] = ss; }
  __syncthreads();
  sum = red[0] + red[2] + red[4] + red[6];
  ss  = red[1] + red[3] + red[5] + red[7];
  const float mu   = sum * (1.0f / NDIM);
  const float var  = ss * (1.0f / NDIM) - mu * mu;
  const float rstd = rsqrtf(var + 1e-12f);
  float4 g  = ((const float4*)gamma)[t];
  float4 be = ((const float4*)beta)[t];
  float4 o;
  o.x = g.x * (y.x - mu) * rstd + be.x;
  o.y = g.y * (y.y - mu) * rstd + be.y;
  o.z = g.z * (y.z - mu) * rstd + be.z;
  o.w = g.w * (y.w - mu) * rstd + be.w;
  hp[t] = o;
}

extern "C" void kernel_launch(void* const* d_in, const int* in_sizes, int n_in,
                              void* d_out, int out_size, void* d_ws,
                              size_t ws_size, hipStream_t stream) {
  const float* x     = (const float*)d_in[0];  // hidden_states [4,4096,4096]
  const float* resid = (const float*)d_in[1];  // input_tensor  [4,4096,1024]
  const float* W     = (const float*)d_in[2];  // [1024,4096]
  const float* b     = (const float*)d_in[3];
  const float* gamma = (const float*)d_in[4];
  const float* beta  = (const float*)d_in[5];
  float* out = (float*)d_out;

  // ws layout: qA 64MB | qW 4MB | 2 uint max-slots  (~68MB total)
  int8_t* qA = (int8_t*)d_ws;
  int8_t* qW = qA + (size_t)MTOT * KDIM;
  unsigned* slots = (unsigned*)(qW + (size_t)NDIM * KDIM);

  hipMemsetAsync(slots, 0, 8, stream);
  maxabs_kernel<<<2048, 256, 0, stream>>>((const float4*)x, MTOT * KDIM / 4, slots);
  maxabs_kernel<<<512, 256, 0, stream>>>((const float4*)W, NDIM * KDIM / 4, slots + 1);
  quant_kernel<<<2048, 256, 0, stream>>>((const float4*)x, (unsigned*)qA,
                                         MTOT * KDIM / 4, slots);
  quant_kernel<<<512, 256, 0, stream>>>((const float4*)W, (unsigned*)qW,
                                        NDIM * KDIM / 4, slots + 1);
  gemm_i8<<<dim3(NDIM / 128, MTOT / 128), 256, 0, stream>>>(qA, qW, out, slots,
                                                            slots + 1);
  ln_kernel<<<MTOT, 256, 0, stream>>>(out, resid, b, gamma, beta);
}

// Round 2
// 606.129 us; speedup vs baseline: 1.1718x; 1.1718x over previous
//
#include <hip/hip_runtime.h>
#include <stdint.h>

#define MTOT  16384   // B*S
#define KDIM  4096    // INTER
#define NDIM  1024    // HID
#define CLIPV 2.5f

typedef __attribute__((ext_vector_type(4)))  int i32x4;
typedef __attribute__((ext_vector_type(16))) int i32x16;
typedef __attribute__((address_space(3))) void lvoid;
typedef __attribute__((address_space(1))) void gvoid;

#define G2L16(g, l) __builtin_amdgcn_global_load_lds((gvoid*)(g), (lvoid*)(l), 16, 0, 0)

// ---------------- max|x| reduction ------------------------------------------------
// Key: m = max|clip(x,±2.5)| = min(max|x|, 2.5). Once any lane in the wave has seen
// |x| >= CLIP, the wave's contribution is exactly CLIP -> stop reading (exact, not
// approximate; worst case data runs the full loop). Block-reduce -> ONE atomic per
// block (R1 had one per wave with no block reduce: 8192 same-address device atomics
// serialized = 170us).
__global__ __launch_bounds__(256) void maxabs_kernel(
    const float4* __restrict__ x, int n4, unsigned* __restrict__ slot) {
  __shared__ float red[4];
  float m = 0.f;
  const int stride = gridDim.x * blockDim.x;
  for (int i = blockIdx.x * blockDim.x + threadIdx.x; i < n4; i += stride) {
    float4 v = x[i];
    m = fmaxf(m, fmaxf(fmaxf(fabsf(v.x), fabsf(v.y)),
                       fmaxf(fabsf(v.z), fabsf(v.w))));
    if (__any(m >= CLIPV)) break;   // exact: result is CLIP regardless of the rest
  }
  m = fminf(m, CLIPV);
#pragma unroll
  for (int off = 32; off > 0; off >>= 1) m = fmaxf(m, __shfl_xor(m, off));
  if ((threadIdx.x & 63) == 0) red[threadIdx.x >> 6] = m;
  __syncthreads();
  if (threadIdx.x == 0) {
    float bm = fmaxf(fmaxf(red[0], red[1]), fmaxf(red[2], red[3]));
    atomicMax(slot, __float_as_uint(bm));
  }
}

// ---------------- symmetric int8 quantization: q = rint(clip(x)*127/m) ------------
__global__ __launch_bounds__(256) void quant_kernel(
    const float4* __restrict__ x, unsigned* __restrict__ q, int n4,
    const unsigned* __restrict__ slot) {
  const float m = fminf(__uint_as_float(*slot), CLIPV);  // m = min(maxabs, clip)
  const float s = 127.0f / m;
  const int stride = gridDim.x * blockDim.x;
#pragma unroll 4
  for (int i = blockIdx.x * blockDim.x + threadIdx.x; i < n4; i += stride) {
    float4 v = x[i];
    int a = (int)rintf(fminf(fmaxf(v.x, -CLIPV), CLIPV) * s);
    int b = (int)rintf(fminf(fmaxf(v.y, -CLIPV), CLIPV) * s);
    int c = (int)rintf(fminf(fmaxf(v.z, -CLIPV), CLIPV) * s);
    int d = (int)rintf(fminf(fmaxf(v.w, -CLIPV), CLIPV) * s);
    q[i] = (unsigned)(a & 255) | ((unsigned)(b & 255) << 8) |
           ((unsigned)(c & 255) << 16) | ((unsigned)(d & 255) << 24);
  }
}

// ---------------- int8 GEMM: C[m][n] = S * sum_k qA[m][k]*qB[n][k] -----------------
// 128x128 block tile, BK=64, 4 waves (2x2), wave tile 64x64 via 2x2 mfma_i32_32x32x32_i8.
// LDS slots (16B) XOR-swizzled: data(row,c) at slot row*4 + (c ^ ((row>>1)&3)).
__global__ __launch_bounds__(256) void gemm_i8(
    const int8_t* __restrict__ qA, const int8_t* __restrict__ qB,
    float* __restrict__ out, const unsigned* __restrict__ slot_x,
    const unsigned* __restrict__ slot_w) {
  __shared__ __align__(16) int8_t As[128 * 64];
  __shared__ __align__(16) int8_t Bs[128 * 64];

  const int t  = threadIdx.x;
  const int l  = t & 63;
  const int w  = t >> 6;
  const int wm = (w & 1) * 64;
  const int wn = (w >> 1) * 64;
  const int lr = l & 31;   // m/n index within 32-tile
  const int lh = l >> 5;   // k-chunk half

  const long m0 = (long)blockIdx.y * 128;
  const long n0 = (long)blockIdx.x * 128;

  i32x16 acc[2][2] = {};

  // staging: thread t covers 16B-slots s0=t and s1=t+256 of each 512-slot tile
  const int s0 = t, s1 = t + 256;
  const int8_t* gA0 = qA + (m0 + (s0 >> 2)) * KDIM + (((s0 & 3) ^ ((s0 >> 3) & 3)) * 16);
  const int8_t* gA1 = qA + (m0 + (s1 >> 2)) * KDIM + (((s1 & 3) ^ ((s1 >> 3) & 3)) * 16);
  const int8_t* gB0 = qB + (n0 + (s0 >> 2)) * KDIM + (((s0 & 3) ^ ((s0 >> 3) & 3)) * 16);
  const int8_t* gB1 = qB + (n0 + (s1 >> 2)) * KDIM + (((s1 & 3) ^ ((s1 >> 3) & 3)) * 16);
  int8_t* lA0 = As + (t & 192) * 16;           // wave-uniform LDS bases
  int8_t* lA1 = As + ((t & 192) + 256) * 16;
  int8_t* lB0 = Bs + (t & 192) * 16;
  int8_t* lB1 = Bs + ((t & 192) + 256) * 16;

  // fragment LDS byte offsets (swizzled), [kk][tile]
  int aoff[2][2], boff[2][2];
#pragma unroll
  for (int kk = 0; kk < 2; ++kk)
#pragma unroll
    for (int mt = 0; mt < 2; ++mt) {
      const int c  = kk * 2 + lh;
      const int ra = wm + mt * 32 + lr;
      const int rb = wn + mt * 32 + lr;
      aoff[kk][mt] = ra * 64 + ((c ^ ((ra >> 1) & 3)) * 16);
      boff[kk][mt] = rb * 64 + ((c ^ ((rb >> 1) & 3)) * 16);
    }

  for (int k0 = 0; k0 < KDIM; k0 += 64) {
    G2L16(gA0 + k0, lA0);
    G2L16(gA1 + k0, lA1);
    G2L16(gB0 + k0, lB0);
    G2L16(gB1 + k0, lB1);
    __syncthreads();   // compiler drains vmcnt(0) before s_barrier
#pragma unroll
    for (int kk = 0; kk < 2; ++kk) {
      i32x4 af0 = *(const i32x4*)(As + aoff[kk][0]);
      i32x4 af1 = *(const i32x4*)(As + aoff[kk][1]);
      i32x4 bf0 = *(const i32x4*)(Bs + boff[kk][0]);
      i32x4 bf1 = *(const i32x4*)(Bs + boff[kk][1]);
      acc[0][0] = __builtin_amdgcn_mfma_i32_32x32x32_i8(af0, bf0, acc[0][0], 0, 0, 0);
      acc[0][1] = __builtin_amdgcn_mfma_i32_32x32x32_i8(af0, bf1, acc[0][1], 0, 0, 0);
      acc[1][0] = __builtin_amdgcn_mfma_i32_32x32x32_i8(af1, bf0, acc[1][0], 0, 0, 0);
      acc[1][1] = __builtin_amdgcn_mfma_i32_32x32x32_i8(af1, bf1, acc[1][1], 0, 0, 0);
    }
    __syncthreads();
  }

  const float mx = fminf(__uint_as_float(*slot_x), CLIPV);
  const float mw = fminf(__uint_as_float(*slot_w), CLIPV);
  const float S  = mx * mw * (1.0f / (127.0f * 127.0f));

  // C/D layout (32x32, dtype-independent): col=lane&31, row=(r&3)+8*(r>>2)+4*(lane>>5)
#pragma unroll
  for (int mt = 0; mt < 2; ++mt)
#pragma unroll
    for (int nt = 0; nt < 2; ++nt)
#pragma unroll
      for (int r = 0; r < 16; ++r) {
        const long row = m0 + wm + mt * 32 + (r & 3) + 8 * (r >> 2) + 4 * lh;
        const long col = n0 + wn + nt * 32 + (l & 31);
        out[row * NDIM + col] = (float)acc[mt][nt][r] * S;
      }
}

// ---------------- fused bias + residual + LayerNorm (in-place on d_out) ------------
__global__ __launch_bounds__(256) void ln_kernel(
    float* __restrict__ h, const float* __restrict__ resid,
    const float* __restrict__ bias, const float* __restrict__ gamma,
    const float* __restrict__ beta) {
  __shared__ float red[8];
  const long row = blockIdx.x;
  const int t = threadIdx.x;
  float4* hp = (float4*)(h + row * NDIM);
  const float4* rp = (const float4*)(resid + row * NDIM);
  float4 y  = hp[t];
  float4 rv = rp[t];
  float4 bv = ((const float4*)bias)[t];
  y.x += rv.x + bv.x; y.y += rv.y + bv.y; y.z += rv.z + bv.z; y.w += rv.w + bv.w;
  float sum = y.x + y.y + y.z + y.w;
  float ss  = y.x * y.x + y.y * y.y + y.z * y.z + y.w * y.w;
#pragma unroll
  for (int off = 32; off > 0; off >>= 1) {
    sum += __shfl_xor(sum, off);
    ss  += __shfl_xor(ss, off);
  }
  if ((t & 63) == 0) { red[(t >> 6) * 2] = sum; red[(t >> 6) * 2 + 1] = ss; }
  __syncthreads();
  sum = red[0] + red[2] + red[4] + red[6];
  ss  = red[1] + red[3] + red[5] + red[7];
  const float mu   = sum * (1.0f / NDIM);
  const float var  = ss * (1.0f / NDIM) - mu * mu;
  const float rstd = rsqrtf(var + 1e-12f);
  float4 g  = ((const float4*)gamma)[t];
  float4 be = ((const float4*)beta)[t];
  float4 o;
  o.x = g.x * (y.x - mu) * rstd + be.x;
  o.y = g.y * (y.y - mu) * rstd + be.y;
  o.z = g.z * (y.z - mu) * rstd + be.z;
  o.w = g.w * (y.w - mu) * rstd + be.w;
  hp[t] = o;
}

extern "C" void kernel_launch(void* const* d_in, const int* in_sizes, int n_in,
                              void* d_out, int out_size, void* d_ws,
                              size_t ws_size, hipStream_t stream) {
  const float* x     = (const float*)d_in[0];  // hidden_states [4,4096,4096]
  const float* resid = (const float*)d_in[1];  // input_tensor  [4,4096,1024]
  const float* W     = (const float*)d_in[2];  // [1024,4096]
  const float* b     = (const float*)d_in[3];
  const float* gamma = (const float*)d_in[4];
  const float* beta  = (const float*)d_in[5];
  float* out = (float*)d_out;

  // ws layout: qA 64MB | qW 4MB | 2 uint max-slots  (~68MB total)
  int8_t* qA = (int8_t*)d_ws;
  int8_t* qW = qA + (size_t)MTOT * KDIM;
  unsigned* slots = (unsigned*)(qW + (size_t)NDIM * KDIM);

  hipMemsetAsync(slots, 0, 8, stream);
  maxabs_kernel<<<2048, 256, 0, stream>>>((const float4*)x, MTOT * KDIM / 4, slots);
  maxabs_kernel<<<512, 256, 0, stream>>>((const float4*)W, NDIM * KDIM / 4, slots + 1);
  quant_kernel<<<2048, 256, 0, stream>>>((const float4*)x, (unsigned*)qA,
                                         MTOT * KDIM / 4, slots);
  quant_kernel<<<512, 256, 0, stream>>>((const float4*)W, (unsigned*)qW,
                                        NDIM * KDIM / 4, slots + 1);
  gemm_i8<<<dim3(NDIM / 128, MTOT / 128), 256, 0, stream>>>(qA, qW, out, slots,
                                                            slots + 1);
  ln_kernel<<<MTOT, 256, 0, stream>>>(out, resid, b, gamma, beta);
}

// Round 3
// 580.660 us; speedup vs baseline: 1.2232x; 1.0439x over previous
//
#include <hip/hip_runtime.h>
#include <stdint.h>

#define MTOT  16384   // B*S
#define KDIM  4096    // INTER
#define NDIM  1024    // HID
#define CLIPV 2.5f

typedef __attribute__((ext_vector_type(4)))  int i32x4;
typedef __attribute__((ext_vector_type(16))) int i32x16;
typedef __attribute__((address_space(3))) void lvoid;
typedef __attribute__((address_space(1))) void gvoid;

#define G2L16(g, l) __builtin_amdgcn_global_load_lds((gvoid*)(g), (lvoid*)(l), 16, 0, 0)

// ---------------- max|x| reduction ------------------------------------------------
// m = max|clip(x,±2.5)| = min(max|x|, 2.5). Once any lane has seen |x| >= CLIP the
// wave's contribution is exactly CLIP -> stop reading (exact). Block-reduce ->
// ONE atomic per block.
__global__ __launch_bounds__(256) void maxabs_kernel(
    const float4* __restrict__ x, int n4, unsigned* __restrict__ slot) {
  __shared__ float red[4];
  float m = 0.f;
  const int stride = gridDim.x * blockDim.x;
  for (int i = blockIdx.x * blockDim.x + threadIdx.x; i < n4; i += stride) {
    float4 v = x[i];
    m = fmaxf(m, fmaxf(fmaxf(fabsf(v.x), fabsf(v.y)),
                       fmaxf(fabsf(v.z), fabsf(v.w))));
    if (__any(m >= CLIPV)) break;   // exact: result is CLIP regardless of the rest
  }
  m = fminf(m, CLIPV);
#pragma unroll
  for (int off = 32; off > 0; off >>= 1) m = fmaxf(m, __shfl_xor(m, off));
  if ((threadIdx.x & 63) == 0) red[threadIdx.x >> 6] = m;
  __syncthreads();
  if (threadIdx.x == 0) {
    float bm = fmaxf(fmaxf(red[0], red[1]), fmaxf(red[2], red[3]));
    atomicMax(slot, __float_as_uint(bm));
  }
}

// ---------------- symmetric int8 quantization: q = rint(clip(x)*127/m) ------------
__global__ __launch_bounds__(256) void quant_kernel(
    const float4* __restrict__ x, unsigned* __restrict__ q, int n4,
    const unsigned* __restrict__ slot) {
  const float m = fminf(__uint_as_float(*slot), CLIPV);  // m = min(maxabs, clip)
  const float s = 127.0f / m;
  const int stride = gridDim.x * blockDim.x;
#pragma unroll 4
  for (int i = blockIdx.x * blockDim.x + threadIdx.x; i < n4; i += stride) {
    float4 v = x[i];
    int a = (int)rintf(fminf(fmaxf(v.x, -CLIPV), CLIPV) * s);
    int b = (int)rintf(fminf(fmaxf(v.y, -CLIPV), CLIPV) * s);
    int c = (int)rintf(fminf(fmaxf(v.z, -CLIPV), CLIPV) * s);
    int d = (int)rintf(fminf(fmaxf(v.w, -CLIPV), CLIPV) * s);
    q[i] = (unsigned)(a & 255) | ((unsigned)(b & 255) << 8) |
           ((unsigned)(c & 255) << 16) | ((unsigned)(d & 255) << 24);
  }
}

// ---------------- int8 GEMM: C[m][n] = S * sum_k qA[m][k]*qB[n][k] -----------------
// 128x128 block tile, BK=128 (32 barrier-drains instead of 64), 4 waves (2x2),
// wave tile 64x64 via 2x2 mfma_i32_32x32x32_i8, 4 k-chunks per stage.
// LDS 16B slots XOR-swizzled within each 128B row: data(row,c) at row*8 + (c^(row&7)).
__global__ __launch_bounds__(256) void gemm_i8(
    const int8_t* __restrict__ qA, const int8_t* __restrict__ qB,
    float* __restrict__ out, const unsigned* __restrict__ slot_x,
    const unsigned* __restrict__ slot_w) {
  __shared__ __align__(16) int8_t As[128 * 128];
  __shared__ __align__(16) int8_t Bs[128 * 128];

  const int t  = threadIdx.x;
  const int l  = t & 63;
  const int w  = t >> 6;
  const int wm = (w & 1) * 64;
  const int wn = (w >> 1) * 64;
  const int lr = l & 31;   // m/n index within 32-tile
  const int lh = l >> 5;   // k-chunk half

  const long m0 = (long)blockIdx.y * 128;
  const long n0 = (long)blockIdx.x * 128;

  i32x16 acc[2][2] = {};

  // staging: 1024 16B-slots per tile, thread t covers slots t+256j (j=0..3).
  // slot s: row=s>>3, stored col=s&7, holds data col (s&7)^(row&7).
  const int8_t* gA[4];
  const int8_t* gB[4];
#pragma unroll
  for (int j = 0; j < 4; ++j) {
    const int s   = t + 256 * j;
    const int row = s >> 3;
    const int cc  = (s & 7) ^ (row & 7);
    gA[j] = qA + (m0 + row) * KDIM + cc * 16;
    gB[j] = qB + (n0 + row) * KDIM + cc * 16;
  }
  // wave-uniform LDS bases: wave w, issue j -> bytes w*1024 + j*4096 (+ lane*16 by HW)
  const int ldsb = (t & 192) * 16;

  // fragment LDS byte offsets (swizzled), [kk][tile]
  int aoff[4][2], boff[4][2];
#pragma unroll
  for (int kk = 0; kk < 4; ++kk)
#pragma unroll
    for (int mt = 0; mt < 2; ++mt) {
      const int c  = kk * 2 + lh;
      const int ra = wm + mt * 32 + lr;
      const int rb = wn + mt * 32 + lr;
      aoff[kk][mt] = ra * 128 + ((c ^ (ra & 7)) * 16);
      boff[kk][mt] = rb * 128 + ((c ^ (rb & 7)) * 16);
    }

  for (int k0 = 0; k0 < KDIM; k0 += 128) {
#pragma unroll
    for (int j = 0; j < 4; ++j) {
      G2L16(gA[j] + k0, As + ldsb + j * 4096);
      G2L16(gB[j] + k0, Bs + ldsb + j * 4096);
    }
    __syncthreads();   // compiler drains vmcnt(0) before s_barrier
#pragma unroll
    for (int kk = 0; kk < 4; ++kk) {
      i32x4 af0 = *(const i32x4*)(As + aoff[kk][0]);
      i32x4 af1 = *(const i32x4*)(As + aoff[kk][1]);
      i32x4 bf0 = *(const i32x4*)(Bs + boff[kk][0]);
      i32x4 bf1 = *(const i32x4*)(Bs + boff[kk][1]);
      acc[0][0] = __builtin_amdgcn_mfma_i32_32x32x32_i8(af0, bf0, acc[0][0], 0, 0, 0);
      acc[0][1] = __builtin_amdgcn_mfma_i32_32x32x32_i8(af0, bf1, acc[0][1], 0, 0, 0);
      acc[1][0] = __builtin_amdgcn_mfma_i32_32x32x32_i8(af1, bf0, acc[1][0], 0, 0, 0);
      acc[1][1] = __builtin_amdgcn_mfma_i32_32x32x32_i8(af1, bf1, acc[1][1], 0, 0, 0);
    }
    __syncthreads();
  }

  const float mx = fminf(__uint_as_float(*slot_x), CLIPV);
  const float mw = fminf(__uint_as_float(*slot_w), CLIPV);
  const float S  = mx * mw * (1.0f / (127.0f * 127.0f));

  // C/D layout (32x32, dtype-independent): col=lane&31, row=(r&3)+8*(r>>2)+4*(lane>>5)
#pragma unroll
  for (int mt = 0; mt < 2; ++mt)
#pragma unroll
    for (int nt = 0; nt < 2; ++nt)
#pragma unroll
      for (int r = 0; r < 16; ++r) {
        const long row = m0 + wm + mt * 32 + (r & 3) + 8 * (r >> 2) + 4 * lh;
        const long col = n0 + wn + nt * 32 + (l & 31);
        out[row * NDIM + col] = (float)acc[mt][nt][r] * S;
      }
}

// ---------------- fused bias + residual + LayerNorm (in-place on d_out) ------------
__global__ __launch_bounds__(256) void ln_kernel(
    float* __restrict__ h, const float* __restrict__ resid,
    const float* __restrict__ bias, const float* __restrict__ gamma,
    const float* __restrict__ beta) {
  __shared__ float red[8];
  const long row = blockIdx.x;
  const int t = threadIdx.x;
  float4* hp = (float4*)(h + row * NDIM);
  const float4* rp = (const float4*)(resid + row * NDIM);
  float4 y  = hp[t];
  float4 rv = rp[t];
  float4 bv = ((const float4*)bias)[t];
  y.x += rv.x + bv.x; y.y += rv.y + bv.y; y.z += rv.z + bv.z; y.w += rv.w + bv.w;
  float sum = y.x + y.y + y.z + y.w;
  float ss  = y.x * y.x + y.y * y.y + y.z * y.z + y.w * y.w;
#pragma unroll
  for (int off = 32; off > 0; off >>= 1) {
    sum += __shfl_xor(sum, off);
    ss  += __shfl_xor(ss, off);
  }
  if ((t & 63) == 0) { red[(t >> 6) * 2] = sum; red[(t >> 6) * 2 + 1] = ss; }
  __syncthreads();
  sum = red[0] + red[2] + red[4] + red[6];
  ss  = red[1] + red[3] + red[5] + red[7];
  const float mu   = sum * (1.0f / NDIM);
  const float var  = ss * (1.0f / NDIM) - mu * mu;
  const float rstd = rsqrtf(var + 1e-12f);
  float4 g  = ((const float4*)gamma)[t];
  float4 be = ((const float4*)beta)[t];
  float4 o;
  o.x = g.x * (y.x - mu) * rstd + be.x;
  o.y = g.y * (y.y - mu) * rstd + be.y;
  o.z = g.z * (y.z - mu) * rstd + be.z;
  o.w = g.w * (y.w - mu) * rstd + be.w;
  hp[t] = o;
}

extern "C" void kernel_launch(void* const* d_in, const int* in_sizes, int n_in,
                              void* d_out, int out_size, void* d_ws,
                              size_t ws_size, hipStream_t stream) {
  const float* x     = (const float*)d_in[0];  // hidden_states [4,4096,4096]
  const float* resid = (const float*)d_in[1];  // input_tensor  [4,4096,1024]
  const float* W     = (const float*)d_in[2];  // [1024,4096]
  const float* b     = (const float*)d_in[3];
  const float* gamma = (const float*)d_in[4];
  const float* beta  = (const float*)d_in[5];
  float* out = (float*)d_out;

  // ws layout: qA 64MB | qW 4MB | 2 uint max-slots  (~68MB total)
  int8_t* qA = (int8_t*)d_ws;
  int8_t* qW = qA + (size_t)MTOT * KDIM;
  unsigned* slots = (unsigned*)(qW + (size_t)NDIM * KDIM);

  hipMemsetAsync(slots, 0, 8, stream);
  maxabs_kernel<<<2048, 256, 0, stream>>>((const float4*)x, MTOT * KDIM / 4, slots);
  maxabs_kernel<<<512, 256, 0, stream>>>((const float4*)W, NDIM * KDIM / 4, slots + 1);
  quant_kernel<<<2048, 256, 0, stream>>>((const float4*)x, (unsigned*)qA,
                                         MTOT * KDIM / 4, slots);
  quant_kernel<<<512, 256, 0, stream>>>((const float4*)W, (unsigned*)qW,
                                        NDIM * KDIM / 4, slots + 1);
  gemm_i8<<<dim3(NDIM / 128, MTOT / 128), 256, 0, stream>>>(qA, qW, out, slots,
                                                            slots + 1);
  ln_kernel<<<MTOT, 256, 0, stream>>>(out, resid, b, gamma, beta);
}

// Round 4
// 563.594 us; speedup vs baseline: 1.2602x; 1.0303x over previous
//
#include <hip/hip_runtime.h>
#include <stdint.h>

#define MTOT  16384   // B*S
#define KDIM  4096    // INTER
#define NDIM  1024    // HID
#define CLIPV 2.5f

typedef __attribute__((ext_vector_type(4)))  int i32x4;
typedef __attribute__((ext_vector_type(16))) int i32x16;
typedef __attribute__((address_space(3))) void lvoid;
typedef __attribute__((address_space(1))) void gvoid;

#define G2L16(g, l) __builtin_amdgcn_global_load_lds((gvoid*)(g), (lvoid*)(l), 16, 0, 0)

// ---------------- max|x| reduction ------------------------------------------------
// m = max|clip(x,±2.5)| = min(max|x|, 2.5). Once any lane has seen |x| >= CLIP the
// wave's contribution is exactly CLIP -> stop reading (exact). Block-reduce ->
// ONE atomic per block.
__global__ __launch_bounds__(256) void maxabs_kernel(
    const float4* __restrict__ x, int n4, unsigned* __restrict__ slot) {
  __shared__ float red[4];
  float m = 0.f;
  const int stride = gridDim.x * blockDim.x;
  for (int i = blockIdx.x * blockDim.x + threadIdx.x; i < n4; i += stride) {
    float4 v = x[i];
    m = fmaxf(m, fmaxf(fmaxf(fabsf(v.x), fabsf(v.y)),
                       fmaxf(fabsf(v.z), fabsf(v.w))));
    if (__any(m >= CLIPV)) break;   // exact: result is CLIP regardless of the rest
  }
  m = fminf(m, CLIPV);
#pragma unroll
  for (int off = 32; off > 0; off >>= 1) m = fmaxf(m, __shfl_xor(m, off));
  if ((threadIdx.x & 63) == 0) red[threadIdx.x >> 6] = m;
  __syncthreads();
  if (threadIdx.x == 0) {
    float bm = fmaxf(fmaxf(red[0], red[1]), fmaxf(red[2], red[3]));
    atomicMax(slot, __float_as_uint(bm));
  }
}

// ---------------- symmetric int8 quantization: q = rint(clip(x)*127/m) ------------
__global__ __launch_bounds__(256) void quant_kernel(
    const float4* __restrict__ x, unsigned* __restrict__ q, int n4,
    const unsigned* __restrict__ slot) {
  const float m = fminf(__uint_as_float(*slot), CLIPV);  // m = min(maxabs, clip)
  const float s = 127.0f / m;
  const int stride = gridDim.x * blockDim.x;
#pragma unroll 4
  for (int i = blockIdx.x * blockDim.x + threadIdx.x; i < n4; i += stride) {
    float4 v = x[i];
    int a = (int)rintf(fminf(fmaxf(v.x, -CLIPV), CLIPV) * s);
    int b = (int)rintf(fminf(fmaxf(v.y, -CLIPV), CLIPV) * s);
    int c = (int)rintf(fminf(fmaxf(v.z, -CLIPV), CLIPV) * s);
    int d = (int)rintf(fminf(fmaxf(v.w, -CLIPV), CLIPV) * s);
    q[i] = (unsigned)(a & 255) | ((unsigned)(b & 255) << 8) |
           ((unsigned)(c & 255) << 16) | ((unsigned)(d & 255) << 24);
  }
}

// ---------------- int8 GEMM: C[m][n] = S * sum_k qA[m][k]*qB[n][k] -----------------
// Block tile 128x256, BK=128. 4 waves in 2x2; wave tile 64x128 (2x4 MFMA grid of
// mfma_i32_32x32x32_i8). Per kk: 6 ds_read_b128 feed 8 MFMAs (was 4:4 at 64x64).
// LDS 16B slots XOR-swizzled within each 128B row: data(row,c) at row*8 + (c^(row&7)).
// acc = 128 VGPRs; __launch_bounds__(256,2) -> 2 blocks/CU (48KB LDS each); the
// other block's waves cover this block's vmcnt(0)+barrier drain.
__global__ __launch_bounds__(256, 2) void gemm_i8(
    const int8_t* __restrict__ qA, const int8_t* __restrict__ qB,
    float* __restrict__ out, const unsigned* __restrict__ slot_x,
    const unsigned* __restrict__ slot_w) {
  __shared__ __align__(16) int8_t As[128 * 128];   // 16 KB
  __shared__ __align__(16) int8_t Bs[256 * 128];   // 32 KB

  const int t  = threadIdx.x;
  const int l  = t & 63;
  const int w  = t >> 6;
  const int wm = (w & 1) * 64;    // wave m-offset
  const int wn = (w >> 1) * 128;  // wave n-offset
  const int lr = l & 31;          // m/n index within 32-tile
  const int lh = l >> 5;          // k-chunk half

  const long m0 = (long)blockIdx.y * 128;
  const long n0 = (long)blockIdx.x * 256;

  i32x16 acc[2][4] = {};

  // staging pointers: slot s covers (row=s>>3, stored col=s&7 -> data col (s&7)^(row&7))
  const int8_t* gA[4];
  const int8_t* gB[8];
#pragma unroll
  for (int j = 0; j < 4; ++j) {
    const int s = t + 256 * j, row = s >> 3, cc = (s & 7) ^ (row & 7);
    gA[j] = qA + (m0 + row) * KDIM + cc * 16;
  }
#pragma unroll
  for (int j = 0; j < 8; ++j) {
    const int s = t + 256 * j, row = s >> 3, cc = (s & 7) ^ (row & 7);
    gB[j] = qB + (n0 + row) * KDIM + cc * 16;
  }
  const int ldsb = (t & 192) * 16;  // wave-uniform: w*1024 (+ j*4096 per issue)

  // fragment address prep (per-lane): addr = base + ((kk*2+lh) ^ mask)*16
  int abase[2], amask[2], bbase[4], bmask[4];
#pragma unroll
  for (int mt = 0; mt < 2; ++mt) {
    const int ra = wm + mt * 32 + lr;
    abase[mt] = ra * 128; amask[mt] = ra & 7;
  }
#pragma unroll
  for (int nt = 0; nt < 4; ++nt) {
    const int rb = wn + nt * 32 + lr;
    bbase[nt] = rb * 128; bmask[nt] = rb & 7;
  }

  for (int k0 = 0; k0 < KDIM; k0 += 128) {
#pragma unroll
    for (int j = 0; j < 4; ++j) G2L16(gA[j] + k0, As + ldsb + j * 4096);
#pragma unroll
    for (int j = 0; j < 8; ++j) G2L16(gB[j] + k0, Bs + ldsb + j * 4096);
    __syncthreads();
#pragma unroll
    for (int kk = 0; kk < 4; ++kk) {
      const int c = kk * 2 + lh;
      i32x4 a0 = *(const i32x4*)(As + abase[0] + ((c ^ amask[0]) << 4));
      i32x4 a1 = *(const i32x4*)(As + abase[1] + ((c ^ amask[1]) << 4));
      i32x4 b0 = *(const i32x4*)(Bs + bbase[0] + ((c ^ bmask[0]) << 4));
      i32x4 b1 = *(const i32x4*)(Bs + bbase[1] + ((c ^ bmask[1]) << 4));
      i32x4 b2 = *(const i32x4*)(Bs + bbase[2] + ((c ^ bmask[2]) << 4));
      i32x4 b3 = *(const i32x4*)(Bs + bbase[3] + ((c ^ bmask[3]) << 4));
      acc[0][0] = __builtin_amdgcn_mfma_i32_32x32x32_i8(a0, b0, acc[0][0], 0, 0, 0);
      acc[1][0] = __builtin_amdgcn_mfma_i32_32x32x32_i8(a1, b0, acc[1][0], 0, 0, 0);
      acc[0][1] = __builtin_amdgcn_mfma_i32_32x32x32_i8(a0, b1, acc[0][1], 0, 0, 0);
      acc[1][1] = __builtin_amdgcn_mfma_i32_32x32x32_i8(a1, b1, acc[1][1], 0, 0, 0);
      acc[0][2] = __builtin_amdgcn_mfma_i32_32x32x32_i8(a0, b2, acc[0][2], 0, 0, 0);
      acc[1][2] = __builtin_amdgcn_mfma_i32_32x32x32_i8(a1, b2, acc[1][2], 0, 0, 0);
      acc[0][3] = __builtin_amdgcn_mfma_i32_32x32x32_i8(a0, b3, acc[0][3], 0, 0, 0);
      acc[1][3] = __builtin_amdgcn_mfma_i32_32x32x32_i8(a1, b3, acc[1][3], 0, 0, 0);
    }
    __syncthreads();
  }

  const float mx = fminf(__uint_as_float(*slot_x), CLIPV);
  const float mw = fminf(__uint_as_float(*slot_w), CLIPV);
  const float S  = mx * mw * (1.0f / (127.0f * 127.0f));

  // C/D layout (32x32, dtype-independent): col=lane&31, row=(r&3)+8*(r>>2)+4*(lane>>5)
#pragma unroll
  for (int mt = 0; mt < 2; ++mt)
#pragma unroll
    for (int r = 0; r < 16; ++r) {
      const long row = m0 + wm + mt * 32 + (r & 3) + 8 * (r >> 2) + 4 * lh;
      float* orow = out + row * NDIM + n0 + wn + lr;
#pragma unroll
      for (int nt = 0; nt < 4; ++nt)
        orow[nt * 32] = (float)acc[mt][nt][r] * S;
    }
}

// ---------------- fused bias + residual + LayerNorm (in-place on d_out) ------------
__global__ __launch_bounds__(256) void ln_kernel(
    float* __restrict__ h, const float* __restrict__ resid,
    const float* __restrict__ bias, const float* __restrict__ gamma,
    const float* __restrict__ beta) {
  __shared__ float red[8];
  const long row = blockIdx.x;
  const int t = threadIdx.x;
  float4* hp = (float4*)(h + row * NDIM);
  const float4* rp = (const float4*)(resid + row * NDIM);
  float4 y  = hp[t];
  float4 rv = rp[t];
  float4 bv = ((const float4*)bias)[t];
  y.x += rv.x + bv.x; y.y += rv.y + bv.y; y.z += rv.z + bv.z; y.w += rv.w + bv.w;
  float sum = y.x + y.y + y.z + y.w;
  float ss  = y.x * y.x + y.y * y.y + y.z * y.z + y.w * y.w;
#pragma unroll
  for (int off = 32; off > 0; off >>= 1) {
    sum += __shfl_xor(sum, off);
    ss  += __shfl_xor(ss, off);
  }
  if ((t & 63) == 0) { red[(t >> 6) * 2] = sum; red[(t >> 6) * 2 + 1] = ss; }
  __syncthreads();
  sum = red[0] + red[2] + red[4] + red[6];
  ss  = red[1] + red[3] + red[5] + red[7];
  const float mu   = sum * (1.0f / NDIM);
  const float var  = ss * (1.0f / NDIM) - mu * mu;
  const float rstd = rsqrtf(var + 1e-12f);
  float4 g  = ((const float4*)gamma)[t];
  float4 be = ((const float4*)beta)[t];
  float4 o;
  o.x = g.x * (y.x - mu) * rstd + be.x;
  o.y = g.y * (y.y - mu) * rstd + be.y;
  o.z = g.z * (y.z - mu) * rstd + be.z;
  o.w = g.w * (y.w - mu) * rstd + be.w;
  hp[t] = o;
}

extern "C" void kernel_launch(void* const* d_in, const int* in_sizes, int n_in,
                              void* d_out, int out_size, void* d_ws,
                              size_t ws_size, hipStream_t stream) {
  const float* x     = (const float*)d_in[0];  // hidden_states [4,4096,4096]
  const float* resid = (const float*)d_in[1];  // input_tensor  [4,4096,1024]
  const float* W     = (const float*)d_in[2];  // [1024,4096]
  const float* b     = (const float*)d_in[3];
  const float* gamma = (const float*)d_in[4];
  const float* beta  = (const float*)d_in[5];
  float* out = (float*)d_out;

  // ws layout: qA 64MB | qW 4MB | 2 uint max-slots  (~68MB total)
  int8_t* qA = (int8_t*)d_ws;
  int8_t* qW = qA + (size_t)MTOT * KDIM;
  unsigned* slots = (unsigned*)(qW + (size_t)NDIM * KDIM);

  hipMemsetAsync(slots, 0, 8, stream);
  maxabs_kernel<<<2048, 256, 0, stream>>>((const float4*)x, MTOT * KDIM / 4, slots);
  maxabs_kernel<<<512, 256, 0, stream>>>((const float4*)W, NDIM * KDIM / 4, slots + 1);
  quant_kernel<<<2048, 256, 0, stream>>>((const float4*)x, (unsigned*)qA,
                                         MTOT * KDIM / 4, slots);
  quant_kernel<<<512, 256, 0, stream>>>((const float4*)W, (unsigned*)qW,
                                        NDIM * KDIM / 4, slots + 1);
  gemm_i8<<<dim3(NDIM / 256, MTOT / 128), 256, 0, stream>>>(qA, qW, out, slots,
                                                            slots + 1);
  ln_kernel<<<MTOT, 256, 0, stream>>>(out, resid, b, gamma, beta);
}